// Round 4
// baseline (10622.019 us; speedup 1.0000x reference)
//
#include <hip/hip_runtime.h>

typedef unsigned int u32;
typedef unsigned long long u64;
typedef short short4v __attribute__((ext_vector_type(4)));
typedef short short8v __attribute__((ext_vector_type(8)));
typedef float f32x4 __attribute__((ext_vector_type(4)));

#define Tn 1024
#define Bn 32
#define Hn 1024
#define BH (Bn * Hn)
#define NWG2 64  // 32 layer-0 WGs + 32 layer-1 WGs

__device__ __forceinline__ float bf2f(short s) {
  u32 u = ((u32)(unsigned short)s) << 16;
  return __builtin_bit_cast(float, u);
}
__device__ __forceinline__ short f2bf(float f) {
  u32 u = __builtin_bit_cast(u32, f);
  u32 r = (u + 0x7fffu + ((u >> 16) & 1u)) >> 16;
  return (short)(unsigned short)r;
}

__device__ __forceinline__ void gl_lds16(const void* g, void* l) {
  __builtin_amdgcn_global_load_lds(
      (const __attribute__((address_space(1))) u32*)g,
      (__attribute__((address_space(3))) u32*)l, 16, 0, 0);
}
// sc0|sc1: agent-coherent read, sourced at the L3 coherence point (no L2
// maintenance needed on either side).
__device__ __forceinline__ void gl_lds16_coh(const void* g, void* l) {
  __builtin_amdgcn_global_load_lds(
      (const __attribute__((address_space(1))) u32*)g,
      (__attribute__((address_space(3))) u32*)l, 16, 0, 0x11);
}
__device__ __forceinline__ void coh_store8(void* p, short4v v) {
  __hip_atomic_store((u64*)p, __builtin_bit_cast(u64, v), __ATOMIC_RELAXED,
                     __HIP_MEMORY_SCOPE_AGENT);
}
// Flag-array barrier: flags[w*32] (128B apart). Arrival: one relaxed agent
// store. Wait: wave 0, lane l polls WG l's flag; divergent while = waits for
// all 64. Caller must __syncthreads() BEFORE (drain vmem) -- flag_set is then
// ordered after all waves' coherent stores have been ACKed at L3.
__device__ __forceinline__ void flag_set(u32* f, u32 v) {
  __hip_atomic_store(f, v, __ATOMIC_RELAXED, __HIP_MEMORY_SCOPE_AGENT);
}
__device__ __forceinline__ void bar_wait(u32* flags, int tid, u32 tgt) {
  if (tid < 64) {
    const u32* fp = flags + tid * 32;
    while (__hip_atomic_load(fp, __ATOMIC_RELAXED, __HIP_MEMORY_SCOPE_AGENT) < tgt)
      __builtin_amdgcn_s_sleep(1);
  }
  __syncthreads();
}

// ---------------- fp32 -> bf16 conversion (vectorized) ----------------
__global__ __launch_bounds__(256) void cvt_bf16(const float* __restrict__ in,
                                                short* __restrict__ out, int n8) {
  int stride = gridDim.x * 256;
  for (int i = blockIdx.x * 256 + threadIdx.x; i < n8; i += stride) {
    const f32x4* p = (const f32x4*)(in + (size_t)i * 8);
    f32x4 a = p[0], b = p[1];
    short8v o;
#pragma unroll
    for (int k = 0; k < 4; k++) { o[k] = f2bf(a[k]); o[k + 4] = f2bf(b[k]); }
    *(short8v*)(out + (size_t)i * 8) = o;
  }
}

// ---------------- C[m][n] = tanh(sum_k A[m][k]*B[n][k] + bias[n]) ----------------
__global__ __launch_bounds__(256) void gemm_tanh(const short* __restrict__ A,
                                                 const short* __restrict__ Bw,
                                                 const float* __restrict__ bias,
                                                 short* __restrict__ C,
                                                 int M, int N, int K) {
  __shared__ short lA[128 * 32];
  __shared__ short lB[128 * 32];
  const int tid = threadIdx.x;
  const int wid = tid >> 6, lane = tid & 63;
  const int lo = lane & 15, hi = lane >> 4;
  const int nbm = M >> 7;
  const int bm = blockIdx.x % nbm, bn = blockIdx.x / nbm;
  const int wm = wid >> 1, wn = wid & 1;

  f32x4 acc[4][4] = {};

  const short* Ab = A + (size_t)(bm * 128 + (tid >> 2)) * K + (tid & 3) * 8;
  const short* Bb = Bw + (size_t)(bn * 128 + (tid >> 2)) * K + (tid & 3) * 8;
  short* lAd = lA + tid * 8;
  short* lBd = lB + tid * 8;

  for (int kt = 0; kt < K; kt += 32) {
    __syncthreads();
    gl_lds16(Ab + kt, lAd);
    gl_lds16(Ab + (size_t)64 * K + kt, lAd + 64 * 32);
    gl_lds16(Bb + kt, lBd);
    gl_lds16(Bb + (size_t)64 * K + kt, lBd + 64 * 32);
    asm volatile("s_waitcnt vmcnt(0)" ::: "memory");
    __syncthreads();
    short8v aF[4], bF[4];
#pragma unroll
    for (int f = 0; f < 4; f++) {
      aF[f] = *(const short8v*)(lA + (wm * 64 + f * 16 + lo) * 32 + hi * 8);
      bF[f] = *(const short8v*)(lB + (wn * 64 + f * 16 + lo) * 32 + hi * 8);
    }
#pragma unroll
    for (int mf = 0; mf < 4; mf++)
#pragma unroll
      for (int nf = 0; nf < 4; nf++)
        acc[mf][nf] = __builtin_amdgcn_mfma_f32_16x16x32_bf16(aF[mf], bF[nf],
                                                              acc[mf][nf], 0, 0, 0);
  }
  const int cm0 = bm * 128 + wm * 64;
  const int cn0 = bn * 128 + wn * 64;
#pragma unroll
  for (int nf = 0; nf < 4; nf++) {
    int col = cn0 + nf * 16 + lo;
    float bv = bias[col];
#pragma unroll
    for (int mf = 0; mf < 4; mf++) {
      int row = cm0 + mf * 16 + hi * 4;
#pragma unroll
      for (int i = 0; i < 4; i++) {
        C[(size_t)(row + i) * N + col] = f2bf(tanhf(acc[mf][nf][i] + bv));
      }
    }
  }
}

// ---------------- fused 2-layer pipelined recurrence ----------------
// 64 WGs: wg<32 run layer 0, wg>=32 run layer 1 skewed one tick behind.
// Tick t: L0 computes h0 step t (consuming ta0[t] + h0img[t&1], publishing
// h0img[(t+1)&1]); L1 computes its step s=t-1 (consuming h0img[t&1] = y0[t-1]
// and h1img[(t-1)&1], publishing h1img[t&1], writing y1[s] fp32).
// 1025 ticks total instead of 2048 barrier steps for two sequential kernels.
// h images are agent-coherent (sc0sc1) bf16, XOR-swizzled (b&7)<<4 so the
// LDS B-frag ds_read_b128 is conflict-free; gl_lds16 destination stays linear
// (swizzle baked into the global image address).
__global__ __launch_bounds__(256, 1) void recur2(
    const short* __restrict__ ta0, const short* __restrict__ w0,
    const float* __restrict__ bhh0, const short* __restrict__ wa1,
    const float* __restrict__ bih1, const short* __restrict__ wr1,
    const float* __restrict__ bhh1, const float* __restrict__ hx,
    short* __restrict__ h0img, short* __restrict__ h1img,
    float* __restrict__ y1, float* __restrict__ hy, u32* __restrict__ flags) {
  __shared__ short hlA[BH];  // 64 KB: L0 h image / L1 y0 image
  __shared__ short hlB[BH];  // 64 KB: L1 h1 image
  const int tid = threadIdx.x;
  const int wg = blockIdx.x;
  const bool isL1 = wg >= 32;
  const int lwg = isL1 ? wg - 32 : wg;
  const int wid = tid >> 6, lane = tid & 63;
  const int lo = lane & 15, hi = lane >> 4;
  const int gw = lwg * 4 + wid;      // 0..127 within layer
  const int jt = gw >> 1, bt = gw & 1;
  const int b = bt * 16 + lo;        // batch row
  const int j0 = jt * 16 + hi * 4;   // 4 output j's
  const int jA = jt * 16 + lo;       // A-frag weight row
  const int koff = hi * 8;

  const u32 hxor = (u32)((b & 7) << 4);
  const u32 hstore = ((u32)(b * 2048 + j0 * 2)) ^ hxor;
  const u32 hbase = (u32)(b * 2048 + koff * 2);

  short* myimg = isL1 ? h1img : h0img;
  f32x4 hreg = *(const f32x4*)(hx + (size_t)(isL1 ? BH : 0) + (size_t)b * Hn + j0);
  f32x4 biasR = *(const f32x4*)((isL1 ? bhh1 : bhh0) + j0);
  f32x4 biasA = {0, 0, 0, 0};
  if (isL1) biasA = *(const f32x4*)(bih1 + j0);

  {  // init my state image, buffer 0
    short4v hv;
#pragma unroll
    for (int i = 0; i < 4; i++) hv[i] = f2bf(hreg[i]);
    coh_store8((char*)myimg + hstore, hv);
  }
  __syncthreads();
  if (tid == 0) flag_set(flags + wg * 32, 1u);
  bar_wait(flags, tid, 1u);

  for (int tick = 0; tick <= Tn; ++tick) {
    if (!isL1) {
      if (tick < Tn) {
        const int t = tick;
        short4v tv = *(const short4v*)(ta0 + (size_t)t * BH + b * Hn + j0);
        const char* src = (const char*)h0img + (size_t)(t & 1) * (BH * 2);
#pragma unroll
        for (int c = 0; c < 16; c++)
          gl_lds16_coh(src + c * 4096 + tid * 16, (char*)hlA + c * 4096 + tid * 16);
        // weight frags: issued while staging is in flight (hides L2 latency)
        short8v wf[32];
#pragma unroll
        for (int s = 0; s < 32; s++)
          wf[s] = *(const short8v*)(w0 + (size_t)jA * Hn + s * 32 + koff);
        asm volatile("s_waitcnt vmcnt(0)" ::: "memory");
        __syncthreads();
        f32x4 a0 = {0, 0, 0, 0}, a1 = {0, 0, 0, 0}, a2 = {0, 0, 0, 0},
              a3 = {0, 0, 0, 0};
#pragma unroll
        for (int s = 0; s < 32; s += 4) {
          short8v v0 = *(const short8v*)((char*)hlA + ((hbase + s * 64) ^ hxor));
          short8v v1 = *(const short8v*)((char*)hlA + ((hbase + s * 64 + 64) ^ hxor));
          short8v v2 = *(const short8v*)((char*)hlA + ((hbase + s * 64 + 128) ^ hxor));
          short8v v3 = *(const short8v*)((char*)hlA + ((hbase + s * 64 + 192) ^ hxor));
          a0 = __builtin_amdgcn_mfma_f32_16x16x32_bf16(wf[s], v0, a0, 0, 0, 0);
          a1 = __builtin_amdgcn_mfma_f32_16x16x32_bf16(wf[s + 1], v1, a1, 0, 0, 0);
          a2 = __builtin_amdgcn_mfma_f32_16x16x32_bf16(wf[s + 2], v2, a2, 0, 0, 0);
          a3 = __builtin_amdgcn_mfma_f32_16x16x32_bf16(wf[s + 3], v3, a3, 0, 0, 0);
        }
        f32x4 xv = (a0 + a1) + (a2 + a3) + biasR;
        f32x4 hn;
#pragma unroll
        for (int i = 0; i < 4; i++) {
          float g = 1.0f / (1.0f + __expf(-xv[i]));
          hn[i] = g * hreg[i] + (1.0f - g) * bf2f(tv[i]);
        }
        hreg = hn;
        short4v hb;
#pragma unroll
        for (int i = 0; i < 4; i++) hb[i] = f2bf(hn[i]);
        coh_store8((char*)h0img + (size_t)((t + 1) & 1) * (BH * 2) + hstore, hb);
      }
    } else {
      if (tick >= 1) {
        const int s_ = tick - 1;
        const char* srcx = (const char*)h0img + (size_t)(tick & 1) * (BH * 2);
        const char* srch = (const char*)h1img + (size_t)(s_ & 1) * (BH * 2);
#pragma unroll
        for (int c = 0; c < 16; c++) {
          gl_lds16_coh(srcx + c * 4096 + tid * 16, (char*)hlA + c * 4096 + tid * 16);
          gl_lds16_coh(srch + c * 4096 + tid * 16, (char*)hlB + c * 4096 + tid * 16);
        }
        short8v wfA[32];
#pragma unroll
        for (int s = 0; s < 32; s++)
          wfA[s] = *(const short8v*)(wa1 + (size_t)jA * Hn + s * 32 + koff);
        asm volatile("s_waitcnt vmcnt(0)" ::: "memory");
        __syncthreads();
        // input-projection matmul: a1 = Wih1 . y0[s]
        f32x4 pA0 = {0, 0, 0, 0}, pA1 = {0, 0, 0, 0}, pA2 = {0, 0, 0, 0},
              pA3 = {0, 0, 0, 0};
#pragma unroll
        for (int s = 0; s < 32; s += 4) {
          short8v v0 = *(const short8v*)((char*)hlA + ((hbase + s * 64) ^ hxor));
          short8v v1 = *(const short8v*)((char*)hlA + ((hbase + s * 64 + 64) ^ hxor));
          short8v v2 = *(const short8v*)((char*)hlA + ((hbase + s * 64 + 128) ^ hxor));
          short8v v3 = *(const short8v*)((char*)hlA + ((hbase + s * 64 + 192) ^ hxor));
          pA0 = __builtin_amdgcn_mfma_f32_16x16x32_bf16(wfA[s], v0, pA0, 0, 0, 0);
          pA1 = __builtin_amdgcn_mfma_f32_16x16x32_bf16(wfA[s + 1], v1, pA1, 0, 0, 0);
          pA2 = __builtin_amdgcn_mfma_f32_16x16x32_bf16(wfA[s + 2], v2, pA2, 0, 0, 0);
          pA3 = __builtin_amdgcn_mfma_f32_16x16x32_bf16(wfA[s + 3], v3, pA3, 0, 0, 0);
        }
        // recurrent matmul: r1 = Whh1 . h1[s-1]
        short8v wfR[32];
#pragma unroll
        for (int s = 0; s < 32; s++)
          wfR[s] = *(const short8v*)(wr1 + (size_t)jA * Hn + s * 32 + koff);
        f32x4 pR0 = {0, 0, 0, 0}, pR1 = {0, 0, 0, 0}, pR2 = {0, 0, 0, 0},
              pR3 = {0, 0, 0, 0};
#pragma unroll
        for (int s = 0; s < 32; s += 4) {
          short8v v0 = *(const short8v*)((char*)hlB + ((hbase + s * 64) ^ hxor));
          short8v v1 = *(const short8v*)((char*)hlB + ((hbase + s * 64 + 64) ^ hxor));
          short8v v2 = *(const short8v*)((char*)hlB + ((hbase + s * 64 + 128) ^ hxor));
          short8v v3 = *(const short8v*)((char*)hlB + ((hbase + s * 64 + 192) ^ hxor));
          pR0 = __builtin_amdgcn_mfma_f32_16x16x32_bf16(wfR[s], v0, pR0, 0, 0, 0);
          pR1 = __builtin_amdgcn_mfma_f32_16x16x32_bf16(wfR[s + 1], v1, pR1, 0, 0, 0);
          pR2 = __builtin_amdgcn_mfma_f32_16x16x32_bf16(wfR[s + 2], v2, pR2, 0, 0, 0);
          pR3 = __builtin_amdgcn_mfma_f32_16x16x32_bf16(wfR[s + 3], v3, pR3, 0, 0, 0);
        }
        f32x4 aS = (pA0 + pA1) + (pA2 + pA3) + biasA;
        f32x4 rS = (pR0 + pR1) + (pR2 + pR3) + biasR;
        f32x4 hn;
#pragma unroll
        for (int i = 0; i < 4; i++) {
          float xt = tanhf(aS[i]);
          float g = 1.0f / (1.0f + __expf(-rS[i]));
          hn[i] = g * hreg[i] + (1.0f - g) * xt;
        }
        hreg = hn;
        short4v hb;
#pragma unroll
        for (int i = 0; i < 4; i++) hb[i] = f2bf(hn[i]);
        coh_store8((char*)h1img + (size_t)(tick & 1) * (BH * 2) + hstore, hb);
        *(f32x4*)(y1 + (size_t)s_ * BH + b * Hn + j0) = hn;
      }
    }
    if (tick != Tn) {
      __syncthreads();  // drains ALL waves' coherent stores before flagging
      if (tid == 0) flag_set(flags + wg * 32, (u32)(tick + 2));
      bar_wait(flags, tid, (u32)(tick + 2));
    }
  }
  *(f32x4*)(hy + (size_t)(isL1 ? BH : 0) + (size_t)b * Hn + j0) = hreg;
}

extern "C" void kernel_launch(void* const* d_in, const int* in_sizes, int n_in,
                              void* d_out, int out_size, void* d_ws, size_t ws_size,
                              hipStream_t stream) {
  const float* x = (const float*)d_in[0];
  const float* hx = (const float*)d_in[1];
  const float* wih0 = (const float*)d_in[2];
  const float* whh0 = (const float*)d_in[3];
  const float* bih0 = (const float*)d_in[4];
  const float* bhh0 = (const float*)d_in[5];
  const float* wih1 = (const float*)d_in[6];
  const float* whh1 = (const float*)d_in[7];
  const float* bih1 = (const float*)d_in[8];
  const float* bhh1 = (const float*)d_in[9];
  float* out = (float*)d_out;  // [T*B*H] y1 then [2*B*H] hy

  char* ws = (char*)d_ws;
  size_t o = 0;
  short* xb = (short*)(ws + o);    o += (size_t)Tn * BH * 2;
  short* tbuf = (short*)(ws + o);  o += (size_t)Tn * BH * 2;
  short* bwih0 = (short*)(ws + o); o += (size_t)Hn * Hn * 2;
  short* bwhh0 = (short*)(ws + o); o += (size_t)Hn * Hn * 2;
  short* bwih1 = (short*)(ws + o); o += (size_t)Hn * Hn * 2;
  short* bwhh1 = (short*)(ws + o); o += (size_t)Hn * Hn * 2;
  short* himg0 = (short*)(ws + o); o += (size_t)2 * BH * 2;
  short* himg1 = (short*)(ws + o); o += (size_t)2 * BH * 2;
  u32* flags = (u32*)(ws + o);     o += NWG2 * 32 * 4;

  hipMemsetAsync(flags, 0, NWG2 * 32 * 4, stream);

  cvt_bf16<<<2048, 256, 0, stream>>>(x, xb, Tn * BH / 8);
  cvt_bf16<<<256, 256, 0, stream>>>(wih0, bwih0, Hn * Hn / 8);
  cvt_bf16<<<256, 256, 0, stream>>>(whh0, bwhh0, Hn * Hn / 8);
  cvt_bf16<<<256, 256, 0, stream>>>(wih1, bwih1, Hn * Hn / 8);
  cvt_bf16<<<256, 256, 0, stream>>>(whh1, bwhh1, Hn * Hn / 8);

  gemm_tanh<<<(Tn * Bn / 128) * (Hn / 128), 256, 0, stream>>>(
      xb, bwih0, bih0, tbuf, Tn * Bn, Hn, Hn);

  recur2<<<NWG2, 256, 0, stream>>>(tbuf, bwhh0, bhh0, bwih1, bih1, bwhh1, bhh1,
                                   hx, himg0, himg1, out,
                                   out + (size_t)Tn * BH, flags);
}

// Round 10
// 5038.790 us; speedup vs baseline: 2.1080x; 2.1080x over previous
//
#include <hip/hip_runtime.h>

typedef unsigned int u32;
typedef unsigned long long u64;
typedef short short4v __attribute__((ext_vector_type(4)));
typedef short short8v __attribute__((ext_vector_type(8)));
typedef float f32x4 __attribute__((ext_vector_type(4)));

#define Tn 1024
#define Bn 32
#define Hn 1024
#define BH (Bn * Hn)
#define NWG 32

__device__ __forceinline__ float bf2f(short s) {
  u32 u = ((u32)(unsigned short)s) << 16;
  return __builtin_bit_cast(float, u);
}
__device__ __forceinline__ short f2bf(float f) {
  u32 u = __builtin_bit_cast(u32, f);
  u32 r = (u + 0x7fffu + ((u >> 16) & 1u)) >> 16;
  return (short)(unsigned short)r;
}

__device__ __forceinline__ void gl_lds16(const void* g, void* l) {
  __builtin_amdgcn_global_load_lds(
      (const __attribute__((address_space(1))) u32*)g,
      (__attribute__((address_space(3))) u32*)l, 16, 0, 0);
}
// sc0|sc1: agent-coherent, transits the L3 coherence point (no L2 maintenance).
__device__ __forceinline__ void gl_lds16_coh(const void* g, void* l) {
  __builtin_amdgcn_global_load_lds(
      (const __attribute__((address_space(1))) u32*)g,
      (__attribute__((address_space(3))) u32*)l, 16, 0, 0x11);
}
__device__ __forceinline__ void coh_store8(void* p, short4v v) {
  __hip_atomic_store((u64*)p, __builtin_bit_cast(u64, v), __ATOMIC_RELAXED,
                     __HIP_MEMORY_SCOPE_AGENT);
}
__device__ __forceinline__ void flag_set(u32* f, u32 v) {
  __hip_atomic_store(f, v, __ATOMIC_RELAXED, __HIP_MEMORY_SCOPE_AGENT);
}

// ---------------- fp32 -> bf16 conversion (vectorized) ----------------
__global__ __launch_bounds__(256) void cvt_bf16(const float* __restrict__ in,
                                                short* __restrict__ out, int n8) {
  int stride = gridDim.x * 256;
  for (int i = blockIdx.x * 256 + threadIdx.x; i < n8; i += stride) {
    const f32x4* p = (const f32x4*)(in + (size_t)i * 8);
    f32x4 a = p[0], b = p[1];
    short8v o;
#pragma unroll
    for (int k = 0; k < 4; k++) { o[k] = f2bf(a[k]); o[k + 4] = f2bf(b[k]); }
    *(short8v*)(out + (size_t)i * 8) = o;
  }
}

// ---------------- C[m][n] = tanh(sum_k A[m][k]*B[n][k] + bias[n]) ----------------
__global__ __launch_bounds__(256) void gemm_tanh(const short* __restrict__ A,
                                                 const short* __restrict__ Bw,
                                                 const float* __restrict__ bias,
                                                 short* __restrict__ C,
                                                 int M, int N, int K) {
  __shared__ short lA[128 * 32];
  __shared__ short lB[128 * 32];
  const int tid = threadIdx.x;
  const int wid = tid >> 6, lane = tid & 63;
  const int lo = lane & 15, hi = lane >> 4;
  const int nbm = M >> 7;
  const int bm = blockIdx.x % nbm, bn = blockIdx.x / nbm;
  const int wm = wid >> 1, wn = wid & 1;

  f32x4 acc[4][4] = {};

  const short* Ab = A + (size_t)(bm * 128 + (tid >> 2)) * K + (tid & 3) * 8;
  const short* Bb = Bw + (size_t)(bn * 128 + (tid >> 2)) * K + (tid & 3) * 8;
  short* lAd = lA + tid * 8;
  short* lBd = lB + tid * 8;

  for (int kt = 0; kt < K; kt += 32) {
    __syncthreads();
    gl_lds16(Ab + kt, lAd);
    gl_lds16(Ab + (size_t)64 * K + kt, lAd + 64 * 32);
    gl_lds16(Bb + kt, lBd);
    gl_lds16(Bb + (size_t)64 * K + kt, lBd + 64 * 32);
    asm volatile("s_waitcnt vmcnt(0)" ::: "memory");
    __syncthreads();
    short8v aF[4], bF[4];
#pragma unroll
    for (int f = 0; f < 4; f++) {
      aF[f] = *(const short8v*)(lA + (wm * 64 + f * 16 + lo) * 32 + hi * 8);
      bF[f] = *(const short8v*)(lB + (wn * 64 + f * 16 + lo) * 32 + hi * 8);
    }
#pragma unroll
    for (int mf = 0; mf < 4; mf++)
#pragma unroll
      for (int nf = 0; nf < 4; nf++)
        acc[mf][nf] = __builtin_amdgcn_mfma_f32_16x16x32_bf16(aF[mf], bF[nf],
                                                              acc[mf][nf], 0, 0, 0);
  }
  const int cm0 = bm * 128 + wm * 64;
  const int cn0 = bn * 128 + wn * 64;
#pragma unroll
  for (int nf = 0; nf < 4; nf++) {
    int col = cn0 + nf * 16 + lo;
    float bv = bias[col];
#pragma unroll
    for (int mf = 0; mf < 4; mf++) {
      int row = cm0 + mf * 16 + hi * 4;
#pragma unroll
      for (int i = 0; i < 4; i++) {
        C[(size_t)(row + i) * N + col] = f2bf(tanhf(acc[mf][nf][i] + bv));
      }
    }
  }
}

// ---------------- persistent recurrence kernel (one layer) ----------------
// g = sigmoid(h @ Whh^T + bhh); h' = g*h + (1-g)*ta[t]
// Batch-split mapping: WG w -> bt = w>>4 (16-batch tile), jg = w&15 (64 j's).
// The two bt-groups are fully independent chains: 16-WG flag barrier each.
// Per step: prefetched ta -> stage 32KB half-image (L3, sc0sc1) -> 32 MFMA
// -> epilogue -> coherent h store -> syncthreads (drain) -> flag_set ->
// y stores + ta prefetch (overlap poll) -> 16-lane flag poll.
__global__ __launch_bounds__(256, 1) void recur(const short* __restrict__ ta,
                                                const short* __restrict__ whh,
                                                const float* __restrict__ bhh,
                                                const float* __restrict__ h0,
                                                short* __restrict__ himg,
                                                short* __restrict__ ybf,
                                                float* __restrict__ yf32,
                                                float* __restrict__ hyout,
                                                u32* __restrict__ flags) {
  __shared__ short hl[16 * Hn];  // 32 KB swizzled half-image
  const int tid = threadIdx.x;
  const int wg = blockIdx.x;
  const int bt = wg >> 4, jg = wg & 15;
  const int wid = tid >> 6, lane = tid & 63;
  const int lo = lane & 15, hi = lane >> 4;
  const int jt = jg * 4 + wid;       // 0..63
  const int b = bt * 16 + lo;        // batch row
  const int j0 = jt * 16 + hi * 4;   // 4 output j's
  const int jA = jt * 16 + lo;       // A-frag weight row
  const int koff = hi * 8;

  const u32 hxor = (u32)((lo & 7) << 4);             // b&7 == lo&7
  const u32 hstore = ((u32)(b * 2048 + j0 * 2)) ^ hxor;
  const u32 lbase = (u32)(lo * 2048 + koff * 2);     // local (staged) base
  const char* srcbase = (const char*)himg + bt * 32768;
  const short* wbase = whh + (size_t)jA * Hn + koff;
  const short* tap = ta + b * Hn + j0;
  u32* gflags = flags + (size_t)bt * 16 * 32;        // my group's flag block

  f32x4 bias = *(const f32x4*)(bhh + j0);
  f32x4 hreg = *(const f32x4*)(h0 + (size_t)b * Hn + j0);

  {  // init h image buffer 0 (agent-coherent)
    short4v hv;
#pragma unroll
    for (int i = 0; i < 4; i++) hv[i] = f2bf(hreg[i]);
    coh_store8((char*)himg + hstore, hv);
  }
  __syncthreads();
  if (tid == 0) flag_set(gflags + jg * 32, 1u);
  // prefetch ta[0] during initial rendezvous
  short4v tv = *(const short4v*)tap;
  if (tid < 16) {
    const u32* fp = gflags + tid * 32;
    while (__hip_atomic_load(fp, __ATOMIC_RELAXED, __HIP_MEMORY_SCOPE_AGENT) < 1u) {}
  }
  __syncthreads();

  for (int t = 0; t < Tn; t++) {
    // weight frags (L2) + half-image stage (L3) all in flight together
    short8v wf[32];
#pragma unroll
    for (int s = 0; s < 32; s++)
      wf[s] = *(const short8v*)(wbase + s * 32);
    const char* src = srcbase + (size_t)(t & 1) * (BH * 2);
#pragma unroll
    for (int c = 0; c < 8; c++)
      gl_lds16_coh(src + c * 4096 + tid * 16, (char*)hl + c * 4096 + tid * 16);
    asm volatile("s_waitcnt vmcnt(0)" ::: "memory");
    __syncthreads();

    f32x4 a0 = {0, 0, 0, 0}, a1 = {0, 0, 0, 0}, a2 = {0, 0, 0, 0}, a3 = {0, 0, 0, 0};
#pragma unroll
    for (int s = 0; s < 32; s += 4) {
      short8v v0 = *(const short8v*)((char*)hl + ((lbase + s * 64) ^ hxor));
      short8v v1 = *(const short8v*)((char*)hl + ((lbase + s * 64 + 64) ^ hxor));
      short8v v2 = *(const short8v*)((char*)hl + ((lbase + s * 64 + 128) ^ hxor));
      short8v v3 = *(const short8v*)((char*)hl + ((lbase + s * 64 + 192) ^ hxor));
      a0 = __builtin_amdgcn_mfma_f32_16x16x32_bf16(wf[s], v0, a0, 0, 0, 0);
      a1 = __builtin_amdgcn_mfma_f32_16x16x32_bf16(wf[s + 1], v1, a1, 0, 0, 0);
      a2 = __builtin_amdgcn_mfma_f32_16x16x32_bf16(wf[s + 2], v2, a2, 0, 0, 0);
      a3 = __builtin_amdgcn_mfma_f32_16x16x32_bf16(wf[s + 3], v3, a3, 0, 0, 0);
    }
    f32x4 xv = (a0 + a1) + (a2 + a3) + bias;
    f32x4 hn;
#pragma unroll
    for (int i = 0; i < 4; i++) {
      float g = 1.0f / (1.0f + __expf(-xv[i]));
      hn[i] = g * hreg[i] + (1.0f - g) * bf2f(tv[i]);
    }
    hreg = hn;
    short4v hb;
#pragma unroll
    for (int i = 0; i < 4; i++) hb[i] = f2bf(hn[i]);
    // publish next h state (agent-coherent)
    coh_store8((char*)himg + (size_t)((t + 1) & 1) * (BH * 2) + hstore, hb);

    if (t != Tn - 1) {
      __syncthreads();  // drains ALL waves' coherent h stores (vmcnt before barrier)
      if (tid == 0) flag_set(gflags + jg * 32, (u32)(t + 2));
      // y stores + next-ta prefetch overlap the rendezvous poll
      if (ybf) *(short4v*)(ybf + (size_t)t * BH + b * Hn + j0) = hb;
      if (yf32) *(f32x4*)(yf32 + (size_t)t * BH + b * Hn + j0) = hn;
      tv = *(const short4v*)(tap + (size_t)(t + 1) * BH);
      if (tid < 16) {
        const u32* fp = gflags + tid * 32;
        u32 tgt = (u32)(t + 2);
        while (__hip_atomic_load(fp, __ATOMIC_RELAXED, __HIP_MEMORY_SCOPE_AGENT) <
               tgt) {}
      }
      __syncthreads();
    } else {
      if (ybf) *(short4v*)(ybf + (size_t)t * BH + b * Hn + j0) = hb;
      if (yf32) *(f32x4*)(yf32 + (size_t)t * BH + b * Hn + j0) = hn;
    }
  }
  *(f32x4*)(hyout + (size_t)b * Hn + j0) = hreg;
}

extern "C" void kernel_launch(void* const* d_in, const int* in_sizes, int n_in,
                              void* d_out, int out_size, void* d_ws, size_t ws_size,
                              hipStream_t stream) {
  const float* x = (const float*)d_in[0];
  const float* hx = (const float*)d_in[1];
  const float* wih0 = (const float*)d_in[2];
  const float* whh0 = (const float*)d_in[3];
  const float* bih0 = (const float*)d_in[4];
  const float* bhh0 = (const float*)d_in[5];
  const float* wih1 = (const float*)d_in[6];
  const float* whh1 = (const float*)d_in[7];
  const float* bih1 = (const float*)d_in[8];
  const float* bhh1 = (const float*)d_in[9];
  float* out = (float*)d_out;  // [T*B*H] y1 then [2*B*H] hy

  char* ws = (char*)d_ws;
  size_t o = 0;
  short* xb = (short*)(ws + o);    o += (size_t)Tn * BH * 2;
  short* tbuf = (short*)(ws + o);  o += (size_t)Tn * BH * 2;
  short* y0 = (short*)(ws + o);    o += (size_t)Tn * BH * 2;
  short* bwih0 = (short*)(ws + o); o += (size_t)Hn * Hn * 2;
  short* bwhh0 = (short*)(ws + o); o += (size_t)Hn * Hn * 2;
  short* bwih1 = (short*)(ws + o); o += (size_t)Hn * Hn * 2;
  short* bwhh1 = (short*)(ws + o); o += (size_t)Hn * Hn * 2;
  short* himg0 = (short*)(ws + o); o += (size_t)2 * BH * 2;
  short* himg1 = (short*)(ws + o); o += (size_t)2 * BH * 2;
  u32* flags = (u32*)(ws + o);     o += 2 * NWG * 32 * 4;

  hipMemsetAsync(flags, 0, 2 * NWG * 32 * 4, stream);

  cvt_bf16<<<2048, 256, 0, stream>>>(x, xb, Tn * BH / 8);
  cvt_bf16<<<256, 256, 0, stream>>>(wih0, bwih0, Hn * Hn / 8);
  cvt_bf16<<<256, 256, 0, stream>>>(whh0, bwhh0, Hn * Hn / 8);
  cvt_bf16<<<256, 256, 0, stream>>>(wih1, bwih1, Hn * Hn / 8);
  cvt_bf16<<<256, 256, 0, stream>>>(whh1, bwhh1, Hn * Hn / 8);

  gemm_tanh<<<(Tn * Bn / 128) * (Hn / 128), 256, 0, stream>>>(
      xb, bwih0, bih0, tbuf, Tn * Bn, Hn, Hn);
  recur<<<NWG, 256, 0, stream>>>(tbuf, bwhh0, bhh0, hx, himg0, y0, nullptr,
                                 out + (size_t)Tn * BH, flags);
  gemm_tanh<<<(Tn * Bn / 128) * (Hn / 128), 256, 0, stream>>>(
      y0, bwih1, bih1, tbuf, Tn * Bn, Hn, Hn);
  recur<<<NWG, 256, 0, stream>>>(tbuf, bwhh1, bhh1, hx + (size_t)BH, himg1,
                                 nullptr, (float*)d_out,
                                 out + (size_t)Tn * BH + (size_t)BH,
                                 flags + NWG * 32);
}

// Round 12
// 3677.225 us; speedup vs baseline: 2.8886x; 1.3703x over previous
//
#include <hip/hip_runtime.h>

typedef unsigned int u32;
typedef unsigned long long u64;
typedef short short4v __attribute__((ext_vector_type(4)));
typedef short short8v __attribute__((ext_vector_type(8)));
typedef float f32x4 __attribute__((ext_vector_type(4)));

#define Tn 1024
#define Bn 32
#define Hn 1024
#define BH (Bn * Hn)

__device__ __forceinline__ float bf2f(short s) {
  u32 u = ((u32)(unsigned short)s) << 16;
  return __builtin_bit_cast(float, u);
}
__device__ __forceinline__ short f2bf(float f) {
  u32 u = __builtin_bit_cast(u32, f);
  u32 r = (u + 0x7fffu + ((u >> 16) & 1u)) >> 16;
  return (short)(unsigned short)r;
}

__device__ __forceinline__ void gl_lds16(const void* g, void* l) {
  __builtin_amdgcn_global_load_lds(
      (const __attribute__((address_space(1))) u32*)g,
      (__attribute__((address_space(3))) u32*)l, 16, 0, 0);
}
// sc0|sc1: agent-coherent, transits the L3 coherence point (no L2 maintenance).
__device__ __forceinline__ void gl_lds16_coh(const void* g, void* l) {
  __builtin_amdgcn_global_load_lds(
      (const __attribute__((address_space(1))) u32*)g,
      (__attribute__((address_space(3))) u32*)l, 16, 0, 0x11);
}
__device__ __forceinline__ void coh_store8(void* p, short4v v) {
  __hip_atomic_store((u64*)p, __builtin_bit_cast(u64, v), __ATOMIC_RELAXED,
                     __HIP_MEMORY_SCOPE_AGENT);
}
__device__ __forceinline__ void flag_set(u32* f, u32 v) {
  __hip_atomic_store(f, v, __ATOMIC_RELAXED, __HIP_MEMORY_SCOPE_AGENT);
}

// ---------------- fp32 -> bf16 conversion (vectorized) ----------------
__global__ __launch_bounds__(256) void cvt_bf16(const float* __restrict__ in,
                                                short* __restrict__ out, int n8) {
  int stride = gridDim.x * 256;
  for (int i = blockIdx.x * 256 + threadIdx.x; i < n8; i += stride) {
    const f32x4* p = (const f32x4*)(in + (size_t)i * 8);
    f32x4 a = p[0], b = p[1];
    short8v o;
#pragma unroll
    for (int k = 0; k < 4; k++) { o[k] = f2bf(a[k]); o[k + 4] = f2bf(b[k]); }
    *(short8v*)(out + (size_t)i * 8) = o;
  }
}

// ---------------- C[m][n] = tanh(sum_k A[m][k]*B[n][k] + bias[n]) ----------------
__global__ __launch_bounds__(256) void gemm_tanh(const short* __restrict__ A,
                                                 const short* __restrict__ Bw,
                                                 const float* __restrict__ bias,
                                                 short* __restrict__ C,
                                                 int M, int N, int K) {
  __shared__ short lA[128 * 32];
  __shared__ short lB[128 * 32];
  const int tid = threadIdx.x;
  const int wid = tid >> 6, lane = tid & 63;
  const int lo = lane & 15, hi = lane >> 4;
  const int nbm = M >> 7;
  const int bm = blockIdx.x % nbm, bn = blockIdx.x / nbm;
  const int wm = wid >> 1, wn = wid & 1;

  f32x4 acc[4][4] = {};

  const short* Ab = A + (size_t)(bm * 128 + (tid >> 2)) * K + (tid & 3) * 8;
  const short* Bb = Bw + (size_t)(bn * 128 + (tid >> 2)) * K + (tid & 3) * 8;
  short* lAd = lA + tid * 8;
  short* lBd = lB + tid * 8;

  for (int kt = 0; kt < K; kt += 32) {
    __syncthreads();
    gl_lds16(Ab + kt, lAd);
    gl_lds16(Ab + (size_t)64 * K + kt, lAd + 64 * 32);
    gl_lds16(Bb + kt, lBd);
    gl_lds16(Bb + (size_t)64 * K + kt, lBd + 64 * 32);
    asm volatile("s_waitcnt vmcnt(0)" ::: "memory");
    __syncthreads();
    short8v aF[4], bF[4];
#pragma unroll
    for (int f = 0; f < 4; f++) {
      aF[f] = *(const short8v*)(lA + (wm * 64 + f * 16 + lo) * 32 + hi * 8);
      bF[f] = *(const short8v*)(lB + (wn * 64 + f * 16 + lo) * 32 + hi * 8);
    }
#pragma unroll
    for (int mf = 0; mf < 4; mf++)
#pragma unroll
      for (int nf = 0; nf < 4; nf++)
        acc[mf][nf] = __builtin_amdgcn_mfma_f32_16x16x32_bf16(aF[mf], bF[nf],
                                                              acc[mf][nf], 0, 0, 0);
  }
  const int cm0 = bm * 128 + wm * 64;
  const int cn0 = bn * 128 + wn * 64;
#pragma unroll
  for (int nf = 0; nf < 4; nf++) {
    int col = cn0 + nf * 16 + lo;
    float bv = bias[col];
#pragma unroll
    for (int mf = 0; mf < 4; mf++) {
      int row = cm0 + mf * 16 + hi * 4;
#pragma unroll
      for (int i = 0; i < 4; i++) {
        C[(size_t)(row + i) * N + col] = f2bf(tanhf(acc[mf][nf][i] + bv));
      }
    }
  }
}

// 32-MFMA chain over a staged half-image (row = batch lo, k-major bf16).
#define MFMA_IMG(IMG, OUTV)                                                     \
  {                                                                             \
    f32x4 a0 = {0, 0, 0, 0}, a1 = {0, 0, 0, 0}, a2 = {0, 0, 0, 0},              \
          a3 = {0, 0, 0, 0};                                                    \
    _Pragma("unroll") for (int s2 = 0; s2 < 32; s2 += 4) {                      \
      short8v v0 = *(const short8v*)((IMG) + ((lbase + s2 * 64) ^ hxor));       \
      short8v v1 = *(const short8v*)((IMG) + ((lbase + s2 * 64 + 64) ^ hxor));  \
      short8v v2 = *(const short8v*)((IMG) + ((lbase + s2 * 64 + 128) ^ hxor)); \
      short8v v3 = *(const short8v*)((IMG) + ((lbase + s2 * 64 + 192) ^ hxor)); \
      a0 = __builtin_amdgcn_mfma_f32_16x16x32_bf16(wf[s2], v0, a0, 0, 0, 0);    \
      a1 = __builtin_amdgcn_mfma_f32_16x16x32_bf16(wf[s2 + 1], v1, a1, 0, 0, 0);\
      a2 = __builtin_amdgcn_mfma_f32_16x16x32_bf16(wf[s2 + 2], v2, a2, 0, 0, 0);\
      a3 = __builtin_amdgcn_mfma_f32_16x16x32_bf16(wf[s2 + 3], v3, a3, 0, 0, 0);\
    }                                                                           \
    OUTV = (a0 + a1) + (a2 + a3);                                               \
  }

// poll helper: lanes 0..7 poll this bt's 8 L0 flags, lanes 8..23 poll the 16
// L1 flags; per-lane targets. Flags are relaxed agent atomics (sc0sc1 loads).
#define POLL(F0TGT, G1TGT)                                                      \
  if (tid < 24) {                                                               \
    const u32* fp;                                                              \
    u32 tg;                                                                     \
    if (tid < 8) { fp = f0 + tid * 32; tg = (u32)(F0TGT); }                     \
    else { fp = g1 + (tid - 8) * 32; tg = (u32)(G1TGT); }                       \
    while (__hip_atomic_load(fp, __ATOMIC_RELAXED, __HIP_MEMORY_SCOPE_AGENT) <  \
           tg) {}                                                               \
  }                                                                             \
  __syncthreads();

// ---------------- fused 2-layer pipelined recurrence ----------------
// 48 WGs x 512 thr. wg<16: layer 0 (2 bt-groups x 8 WGs, 8 jt/WG, one
// 32-MFMA chain per wave -- the proven R10 structure). wg>=16: layer 1
// (2 bt-groups x 16 WGs); 8 waves = 4 jt x {A: Wih1*y0, R: Whh1*h1}; A/R
// partials combined via 4KB LDS scratch. L1 consumes y0 directly from the
// h0 image ring (4 buffers, slack 3) -- no y0 buffer, no second GEMM.
// Flags: f0[bt][8] (L0 groups), g1[bt][16] (L1 groups), monotone step tags.
// L0 back-pressure: before step t+1 require g1 >= t-1 (ring-slot reuse safe:
// write at T clobbers h0_{T-3}, last read by L1 step T-4 <=> flag T-2).
// NOTE (R11 fix): store offsets use b*2048 which ALREADY includes bt*32768
// (b = bt*16+lo) -- do not add bt*32768 again on the store side.
__global__ __launch_bounds__(512, 2) void recur2(
    const short* __restrict__ ta0, const short* __restrict__ w0,
    const float* __restrict__ bhh0, const short* __restrict__ wa1,
    const float* __restrict__ bih1, const short* __restrict__ wr1,
    const float* __restrict__ bhh1, const float* __restrict__ hx,
    short* __restrict__ h0img, short* __restrict__ h1img,
    float* __restrict__ y1, float* __restrict__ hy, u32* __restrict__ flags) {
  __shared__ short hlY[16 * Hn];   // 32 KB (L0: h0 half; L1: y0 half)
  __shared__ short hlH[16 * Hn];   // 32 KB (L1: h1 half)
  __shared__ f32x4 scr[4][64];     // 4 KB  (L1 A/R combine)
  const int tid = threadIdx.x;
  const int wg = blockIdx.x;
  const int lane = tid & 63, wid = tid >> 6;
  const int lo = lane & 15, hi = lane >> 4;
  const int koff = hi * 8;
  const u32 hxor = (u32)((lo & 7) << 4);
  const u32 lbase = (u32)(lo * 2048 + koff * 2);

  if (wg < 16) {
    // ---------------- layer 0 ----------------
    const int bt = wg >> 3, jg = wg & 7;
    const int jt = jg * 8 + wid;      // 0..63
    const int b = bt * 16 + lo;
    const int j0 = jt * 16 + hi * 4;
    const int jA = jt * 16 + lo;
    const u32 hstore = ((u32)(b * 2048 + j0 * 2)) ^ hxor;  // includes bt offset
    const short* wbase = w0 + (size_t)jA * Hn + koff;
    const short* tap = ta0 + b * Hn + j0;
    u32* f0 = flags + bt * 256;
    u32* g1 = flags + 512 + bt * 512;
    u32* myf = f0 + jg * 32;

    f32x4 bias = *(const f32x4*)(bhh0 + j0);
    f32x4 hreg = *(const f32x4*)(hx + (size_t)b * Hn + j0);
    {
      short4v hv;
#pragma unroll
      for (int i = 0; i < 4; i++) hv[i] = f2bf(hreg[i]);
      coh_store8((char*)h0img + hstore, hv);
    }
    __syncthreads();
    if (tid == 0) flag_set(myf, 1u);
    short4v tv = *(const short4v*)tap;
    POLL(1u, 0u);

    for (int t = 0; t < Tn; ++t) {
      short8v wf[32];
#pragma unroll
      for (int s = 0; s < 32; s++) wf[s] = *(const short8v*)(wbase + s * 32);
      const char* src =
          (const char*)h0img + (size_t)(t & 3) * (BH * 2) + bt * 32768;
#pragma unroll
      for (int c = 0; c < 4; c++)
        gl_lds16_coh(src + c * 8192 + tid * 16, (char*)hlY + c * 8192 + tid * 16);
      asm volatile("s_waitcnt vmcnt(0)" ::: "memory");
      __syncthreads();

      f32x4 xv;
      MFMA_IMG((const char*)hlY, xv);
      xv = xv + bias;
      f32x4 hn;
#pragma unroll
      for (int i = 0; i < 4; i++) {
        float g = 1.0f / (1.0f + __expf(-xv[i]));
        hn[i] = g * hreg[i] + (1.0f - g) * bf2f(tv[i]);
      }
      hreg = hn;
      short4v hb;
#pragma unroll
      for (int i = 0; i < 4; i++) hb[i] = f2bf(hn[i]);
      coh_store8((char*)h0img + (size_t)((t + 1) & 3) * (BH * 2) + hstore, hb);
      __syncthreads();  // drains all waves' coherent h stores
      if (tid == 0) flag_set(myf, (u32)(t + 2));
      if (t != Tn - 1) {
        tv = *(const short4v*)(tap + (size_t)(t + 1) * BH);
        POLL(t + 2, (t >= 1) ? (t - 1) : 0);
      }
    }
    *(f32x4*)(hy + (size_t)b * Hn + j0) = hreg;
  } else {
    // ---------------- layer 1 ----------------
    const int lwg = wg - 16;
    const int bt = lwg >> 4, wj = lwg & 15;
    const int jtq = wid >> 1, role = wid & 1;  // 0 = A (Wih1*y0), 1 = R (Whh1*h1)
    const int myjt = wj * 4 + jtq;             // 0..63
    const int b = bt * 16 + lo;
    const int j0 = myjt * 16 + hi * 4;
    const int jA = myjt * 16 + lo;
    const u32 hstore = ((u32)(b * 2048 + j0 * 2)) ^ hxor;  // includes bt offset
    const short* wbase = (role ? wr1 : wa1) + (size_t)jA * Hn + koff;
    u32* f0 = flags + bt * 256;
    u32* g1 = flags + 512 + bt * 512;
    u32* myf = g1 + wj * 32;

    f32x4 bias = *(const f32x4*)((role ? bhh1 : bih1) + j0);
    f32x4 hreg = {0, 0, 0, 0};
    if (!role) {
      hreg = *(const f32x4*)(hx + (size_t)BH + (size_t)b * Hn + j0);
      short4v hv;
#pragma unroll
      for (int i = 0; i < 4; i++) hv[i] = f2bf(hreg[i]);
      coh_store8((char*)h1img + hstore, hv);
    }
    __syncthreads();
    if (tid == 0) flag_set(myf, 1u);
    POLL(2u, 1u);

    for (int s = 0; s < Tn; ++s) {
      short8v wf[32];
#pragma unroll
      for (int k = 0; k < 32; k++) wf[k] = *(const short8v*)(wbase + k * 32);
      const char* srcY =
          (const char*)h0img + (size_t)((s + 1) & 3) * (BH * 2) + bt * 32768;
      const char* srcH =
          (const char*)h1img + (size_t)(s & 1) * (BH * 2) + bt * 32768;
#pragma unroll
      for (int c = 0; c < 4; c++) {
        gl_lds16_coh(srcY + c * 8192 + tid * 16, (char*)hlY + c * 8192 + tid * 16);
        gl_lds16_coh(srcH + c * 8192 + tid * 16, (char*)hlH + c * 8192 + tid * 16);
      }
      asm volatile("s_waitcnt vmcnt(0)" ::: "memory");
      __syncthreads();

      const char* img = role ? (const char*)hlH : (const char*)hlY;
      f32x4 xv;
      MFMA_IMG(img, xv);
      xv = xv + bias;
      if (role) scr[jtq][lane] = xv;
      __syncthreads();
      f32x4 hn = {0, 0, 0, 0};
      if (!role) {
        f32x4 rS = scr[jtq][lane];
#pragma unroll
        for (int i = 0; i < 4; i++) {
          float g = 1.0f / (1.0f + __expf(-rS[i]));
          float ht = tanhf(xv[i]);
          hn[i] = g * hreg[i] + (1.0f - g) * ht;
        }
        hreg = hn;
        short4v hb;
#pragma unroll
        for (int i = 0; i < 4; i++) hb[i] = f2bf(hn[i]);
        coh_store8((char*)h1img + (size_t)((s + 1) & 1) * (BH * 2) + hstore, hb);
      }
      __syncthreads();  // drains role-0 coherent h1 stores
      if (tid == 0) flag_set(myf, (u32)(s + 2));
      if (!role) *(f32x4*)(y1 + (size_t)s * BH + b * Hn + j0) = hn;
      if (s != Tn - 1) {
        POLL(s + 3, s + 2);
      }
    }
    if (!role) *(f32x4*)(hy + (size_t)BH + (size_t)b * Hn + j0) = hreg;
  }
}

extern "C" void kernel_launch(void* const* d_in, const int* in_sizes, int n_in,
                              void* d_out, int out_size, void* d_ws, size_t ws_size,
                              hipStream_t stream) {
  const float* x = (const float*)d_in[0];
  const float* hx = (const float*)d_in[1];
  const float* wih0 = (const float*)d_in[2];
  const float* whh0 = (const float*)d_in[3];
  const float* bih0 = (const float*)d_in[4];
  const float* bhh0 = (const float*)d_in[5];
  const float* wih1 = (const float*)d_in[6];
  const float* whh1 = (const float*)d_in[7];
  const float* bih1 = (const float*)d_in[8];
  const float* bhh1 = (const float*)d_in[9];
  float* out = (float*)d_out;  // [T*B*H] y1 then [2*B*H] hy

  char* ws = (char*)d_ws;
  size_t o = 0;
  short* xb = (short*)(ws + o);    o += (size_t)Tn * BH * 2;
  short* tbuf = (short*)(ws + o);  o += (size_t)Tn * BH * 2;
  short* bwih0 = (short*)(ws + o); o += (size_t)Hn * Hn * 2;
  short* bwhh0 = (short*)(ws + o); o += (size_t)Hn * Hn * 2;
  short* bwih1 = (short*)(ws + o); o += (size_t)Hn * Hn * 2;
  short* bwhh1 = (short*)(ws + o); o += (size_t)Hn * Hn * 2;
  short* h0img = (short*)(ws + o); o += (size_t)4 * BH * 2;  // 4-buffer ring
  short* h1img = (short*)(ws + o); o += (size_t)2 * BH * 2;  // double buffer
  u32* flags = (u32*)(ws + o);     o += 6144;

  hipMemsetAsync(flags, 0, 6144, stream);

  cvt_bf16<<<2048, 256, 0, stream>>>(x, xb, Tn * BH / 8);
  cvt_bf16<<<256, 256, 0, stream>>>(wih0, bwih0, Hn * Hn / 8);
  cvt_bf16<<<256, 256, 0, stream>>>(whh0, bwhh0, Hn * Hn / 8);
  cvt_bf16<<<256, 256, 0, stream>>>(wih1, bwih1, Hn * Hn / 8);
  cvt_bf16<<<256, 256, 0, stream>>>(whh1, bwhh1, Hn * Hn / 8);

  gemm_tanh<<<(Tn * Bn / 128) * (Hn / 128), 256, 0, stream>>>(
      xb, bwih0, bih0, tbuf, Tn * Bn, Hn, Hn);

  recur2<<<48, 512, 0, stream>>>(tbuf, bwhh0, bhh0, bwih1, bih1, bwhh1, bhh1,
                                 hx, h0img, h1img, out, out + (size_t)Tn * BH,
                                 flags);
}